// Round 1
// 667.176 us; speedup vs baseline: 1.0172x; 1.0172x over previous
//
#include <hip/hip_runtime.h>
#include <hip/hip_bf16.h>

// SparseMLP: per-expert  out = gelu_tanh(x @ w1^T) @ w2
// E=8, T=2048, H=1024, F=4096. fp32 in/out, bf16 MFMA compute.
//
// R2: XOR-swizzled LDS (conflicts 5e7 -> 1.7e7).
// R3: 32x32x16 MFMA + XCD rasters. GEMMs 2x ~199us = ~690 TF each -> the
//     2-barrier-per-K-step structural ceiling (MfmaUtil 30%).
// R4: 256x256 tile / 8 waves / 8-phase schedule (T2+T3+T4+T5 stack):
//     - per K-tile: 4 C-quadrant phases {ds_read | stage-issue | s_barrier |
//       lgkmcnt(0) | setprio(1) 8xMFMA setprio(0) | s_barrier}
//     - counted vmcnt(4) once per K-tile (loads stay in flight across
//       barriers; never vmcnt(0) in steady state)
//     - prefetch: kt+1's A quarters issued ph1-2 (into free buffer),
//       kt+2's B quarters issued ph3-4 (into current buffer; B fully
//       consumed into registers by ph2's closing barrier -> WAR-safe)
//     - 128KB LDS double buffer, 1 block/CU, acc 4x2 f32x16
//     - swizzle gains octet term: phys_chunk = cL ^ (row&7) ^ ((row>>3&3)<<1)
//       (kills residual 4-way bank conflicts of rows r, r+8, r+16, r+24)

typedef __bf16 bf16x8 __attribute__((ext_vector_type(8)));
typedef float  f32x16 __attribute__((ext_vector_type(16)));

__device__ inline unsigned short f2b(float f) {
    unsigned u = __float_as_uint(f);
    u += 0x7fff + ((u >> 16) & 1);   // round-to-nearest-even
    return (unsigned short)(u >> 16);
}

// element offset (within a 64-elem row) of logical 8-bf16 chunk cL
__device__ inline int swz(int row, int cL) {
    return (cL ^ (row & 7) ^ (((row >> 3) & 3) << 1)) << 3;
}

// ---------------- cast fp32 -> bf16 (flat, vectorized) ----------------
__global__ void cast_f32_bf16(const float* __restrict__ in,
                              unsigned short* __restrict__ out, int n4) {
    int i = blockIdx.x * 256 + threadIdx.x;
    if (i >= n4) return;
    float4 v = ((const float4*)in)[i];
    ushort4 o;
    o.x = f2b(v.x); o.y = f2b(v.y); o.z = f2b(v.z); o.w = f2b(v.w);
    ((ushort4*)out)[i] = o;
}

// ------------- transpose-cast w2: fp32 [E,F,H] -> bf16 [E,H,F] -------------
// 64(f) x 32(h) tile; ushort2 stores -> 128B fully-coalesced writes.
__global__ void transpose_cast(const float* __restrict__ in,
                               unsigned short* __restrict__ out, int F, int H) {
    __shared__ float tile[64][33];
    const int e = blockIdx.z;
    const int f0 = blockIdx.y * 64, h0 = blockIdx.x * 32;
    const float* src = in + (long long)e * F * H;
    unsigned short* dst = out + (long long)e * F * H;
    const int tx = threadIdx.x, ty = threadIdx.y;   // 32 x 8
#pragma unroll
    for (int i = 0; i < 64; i += 8)
        tile[ty + i][tx] = src[(long long)(f0 + ty + i) * H + h0 + tx];
    __syncthreads();
#pragma unroll
    for (int i = 0; i < 32; i += 8) {
        const int h = ty + i;
        ushort2 o;
        o.x = f2b(tile[2 * tx][h]);
        o.y = f2b(tile[2 * tx + 1][h]);
        *(ushort2*)&dst[(long long)(h0 + h) * F + f0 + 2 * tx] = o;
    }
}

// ---------------- bf16 GEMM, C = A @ B^T, 256x256 tile, 8-phase ----------
// A: [E][M][K] bf16 (K-major), B: [E][N][K] bf16 (K-major), C: [E][M][N]
// 512 threads = 8 waves (2M x 4N); wave owns 128x64; MFMA 32x32x16.
// LDS per operand per buffer: [256 rows][8 chunks of 8 bf16], chunk-swizzled.
// Staging unit = 64-row "quarter" (512 thr x 16B = 8KB = one quarter).
#define STG(dst, g, q, kt)                                                    \
    __builtin_amdgcn_global_load_lds(                                         \
        (const __attribute__((address_space(1))) void*)((g) +                 \
            (long long)((q) * 64 + srow) * K + ((kt) << 6) + scol),           \
        (__attribute__((address_space(3))) void*)(&(dst)[(q) * 4096 + sdst]), \
        16, 0, 0)

template <bool GELU, typename CT>
__global__ __launch_bounds__(512) void gemm_bt8(
    const unsigned short* __restrict__ A,
    const unsigned short* __restrict__ B,
    CT* __restrict__ C, int M, int N, int K) {
    // XCD-chunked bijective raster (nwg % 8 == 0): each XCD owns a contiguous
    // wgid range -> concurrent blocks share K-window slabs in its 4MB L2.
    const int nwg = gridDim.x;
    const int id = blockIdx.x;
    const int wgid = (id & 7) * (nwg >> 3) + (id >> 3);
    const int ntn = N >> 8;
    const int tpe = (M >> 8) * ntn;
    const int e = wgid / tpe;
    const int rem = wgid - e * tpe;
    const int bm = (rem / ntn) << 8;
    const int bn = (rem % ntn) << 8;
    A += (long long)e * M * K;
    B += (long long)e * N * K;
    C += (long long)e * M * N;

    __shared__ __align__(16) unsigned short sA[2][256 * 64];
    __shared__ __align__(16) unsigned short sB[2][256 * 64];

    const int tid = threadIdx.x;
    const int lane = tid & 63;
    const int wid = tid >> 6;
    const int half = lane >> 5, r32 = lane & 31;
    const int wm = (wid >> 2) * 128;   // wave M offset in tile
    const int wn = (wid & 3) * 64;     // wave N offset in tile

    // staging per-thread constants (row&7 and (row>>3)&3 are quarter-invariant)
    const int srow = tid >> 3;                                         // 0..63
    const int scol = ((tid & 7) ^ ((tid >> 3) & 7) ^ (((tid >> 6) & 3) << 1)) << 3;
    const int sdst = tid * 8;

    const unsigned short* gA = A + (long long)bm * K;
    const unsigned short* gB = B + (long long)bn * K;
    const int NT = K >> 6;

    // ---- prologue: kt0 fully (8 quarters) + kt1's B quarters; vmcnt(4)
    //      leaves kt1's B in flight = steady-state entry.
    {
        unsigned short* dA = sA[0];
        unsigned short* dB = sB[0];
        STG(dB, gB, 0, 0); STG(dB, gB, 1, 0); STG(dB, gB, 2, 0); STG(dB, gB, 3, 0);
        STG(dA, gA, 0, 0); STG(dA, gA, 2, 0); STG(dA, gA, 1, 0); STG(dA, gA, 3, 0);
        if (NT > 1) {
            unsigned short* dB1 = sB[1];
            STG(dB1, gB, 0, 1); STG(dB1, gB, 1, 1); STG(dB1, gB, 2, 1); STG(dB1, gB, 3, 1);
            asm volatile("s_waitcnt vmcnt(4)" ::: "memory");
        } else {
            asm volatile("s_waitcnt vmcnt(0)" ::: "memory");
        }
    }
    __builtin_amdgcn_s_barrier();

    f32x16 acc[4][2] = {};
    bf16x8 af[2][4], bf[2][4];

    for (int kt = 0; kt < NT; ++kt) {
        const int p = kt & 1;
        const unsigned short* cA = sA[p];
        const unsigned short* cB = sB[p];
        unsigned short* nA = sA[p ^ 1];   // kt+1's A buffer (fully free)
        unsigned short* stB = sB[p];      // kt+2's B buffer (= current, B done after ph2)
        const bool pf1 = (kt + 1 < NT), pf2 = (kt + 2 < NT);

        // ---------- phase 1: Q(qm=0, qn=0) ----------
#pragma unroll
        for (int mb = 0; mb < 2; ++mb) {
            const int row = wm + mb * 32 + r32;
#pragma unroll
            for (int ks = 0; ks < 4; ++ks)
                af[mb][ks] = *(const bf16x8*)&cA[row * 64 + swz(row, ks * 2 + half)];
        }
        {
            const int row = wn + r32;
#pragma unroll
            for (int ks = 0; ks < 4; ++ks)
                bf[0][ks] = *(const bf16x8*)&cB[row * 64 + swz(row, ks * 2 + half)];
        }
        if (pf1) { STG(nA, gA, 0, kt + 1); STG(nA, gA, 2, kt + 1); }
        __builtin_amdgcn_s_barrier();
        asm volatile("s_waitcnt lgkmcnt(0)" ::: "memory");
        __builtin_amdgcn_s_setprio(1);
#pragma unroll
        for (int ks = 0; ks < 4; ++ks)
#pragma unroll
            for (int mb = 0; mb < 2; ++mb)
                acc[mb][0] = __builtin_amdgcn_mfma_f32_32x32x16_bf16(
                    af[mb][ks], bf[0][ks], acc[mb][0], 0, 0, 0);
        __builtin_amdgcn_s_setprio(0);
        __builtin_amdgcn_s_barrier();

        // ---------- phase 2: Q(0,1) ----------
        {
            const int row = wn + 32 + r32;
#pragma unroll
            for (int ks = 0; ks < 4; ++ks)
                bf[1][ks] = *(const bf16x8*)&cB[row * 64 + swz(row, ks * 2 + half)];
        }
        if (pf1) { STG(nA, gA, 1, kt + 1); STG(nA, gA, 3, kt + 1); }
        __builtin_amdgcn_s_barrier();
        asm volatile("s_waitcnt lgkmcnt(0)" ::: "memory");
        __builtin_amdgcn_s_setprio(1);
#pragma unroll
        for (int ks = 0; ks < 4; ++ks)
#pragma unroll
            for (int mb = 0; mb < 2; ++mb)
                acc[mb][1] = __builtin_amdgcn_mfma_f32_32x32x16_bf16(
                    af[mb][ks], bf[1][ks], acc[mb][1], 0, 0, 0);
        __builtin_amdgcn_s_setprio(0);
        __builtin_amdgcn_s_barrier();

        // ---------- phase 3: Q(1,0) ----------  (B LDS region now dead -> stage kt+2 B)
#pragma unroll
        for (int mb = 0; mb < 2; ++mb) {
            const int row = wm + 64 + mb * 32 + r32;
#pragma unroll
            for (int ks = 0; ks < 4; ++ks)
                af[mb][ks] = *(const bf16x8*)&cA[row * 64 + swz(row, ks * 2 + half)];
        }
        if (pf2) { STG(stB, gB, 0, kt + 2); STG(stB, gB, 1, kt + 2); }
        __builtin_amdgcn_s_barrier();
        asm volatile("s_waitcnt lgkmcnt(0)" ::: "memory");
        __builtin_amdgcn_s_setprio(1);
#pragma unroll
        for (int ks = 0; ks < 4; ++ks)
#pragma unroll
            for (int mb = 0; mb < 2; ++mb)
                acc[2 + mb][0] = __builtin_amdgcn_mfma_f32_32x32x16_bf16(
                    af[mb][ks], bf[0][ks], acc[2 + mb][0], 0, 0, 0);
        __builtin_amdgcn_s_setprio(0);
        __builtin_amdgcn_s_barrier();

        // ---------- phase 4: Q(1,1) ----------
        if (pf2) { STG(stB, gB, 2, kt + 2); STG(stB, gB, 3, kt + 2); }
        __builtin_amdgcn_s_setprio(1);
#pragma unroll
        for (int ks = 0; ks < 4; ++ks)
#pragma unroll
            for (int mb = 0; mb < 2; ++mb)
                acc[2 + mb][1] = __builtin_amdgcn_mfma_f32_32x32x16_bf16(
                    af[mb][ks], bf[1][ks], acc[2 + mb][1], 0, 0, 0);
        __builtin_amdgcn_s_setprio(0);
        // K-tile boundary: kt+1 must be fully landed; kt+2's 4 B-loads stay
        // in flight (counted vmcnt -- the T4 lever).
        if (pf2) asm volatile("s_waitcnt vmcnt(4)" ::: "memory");
        else     asm volatile("s_waitcnt vmcnt(0)" ::: "memory");
        __builtin_amdgcn_s_barrier();
    }

    // ---- epilogue: 32x32 C/D layout col=lane&31, row=(r&3)+8*(r>>2)+4*half ----
#pragma unroll
    for (int mb = 0; mb < 4; ++mb) {
        const int row_base = bm + wm + mb * 32;
#pragma unroll
        for (int nb = 0; nb < 2; ++nb) {
            const int col = bn + wn + nb * 32 + r32;
#pragma unroll
            for (int r = 0; r < 16; ++r) {
                const int row = row_base + (r & 3) + 8 * (r >> 2) + 4 * half;
                float v = acc[mb][nb][r];
                if (GELU) {
                    // gelu_tanh(v) = v * sigmoid(2*0.79788456*(v + 0.044715 v^3))
                    float t = 1.5957691216057308f * (v + 0.044715f * v * v * v);
                    v = v / (1.0f + __expf(-t));
                }
                if constexpr (sizeof(CT) == 2) {
                    ((unsigned short*)C)[(long long)row * N + col] = f2b(v);
                } else {
                    ((float*)C)[(long long)row * N + col] = v;
                }
            }
        }
    }
}
#undef STG

extern "C" void kernel_launch(void* const* d_in, const int* in_sizes, int n_in,
                              void* d_out, int out_size, void* d_ws, size_t ws_size,
                              hipStream_t stream) {
    constexpr int E = 8, T = 2048, H = 1024, F = 4096;
    const float* x  = (const float*)d_in[0];   // [E,T,H]
    const float* w1 = (const float*)d_in[1];   // [E,F,H]
    const float* w2 = (const float*)d_in[2];   // [E,F,H]
    float* out = (float*)d_out;                // [E,T,H]

    unsigned short* xb  = (unsigned short*)d_ws;          // E*T*H bf16
    unsigned short* w1b = xb  + (size_t)E * T * H;        // E*F*H bf16
    unsigned short* w2t = w1b + (size_t)E * F * H;        // E*H*F bf16 (transposed)
    unsigned short* ab  = w2t + (size_t)E * F * H;        // E*T*F bf16 (gelu act)

    const int nx = E * T * H / 4, nw = E * F * H / 4;
    cast_f32_bf16<<<(nx + 255) / 256, 256, 0, stream>>>(x, xb, nx);
    cast_f32_bf16<<<(nw + 255) / 256, 256, 0, stream>>>(w1, w1b, nw);
    transpose_cast<<<dim3(H / 32, F / 64, E), dim3(32, 8), 0, stream>>>(w2, w2t, F, H);

    // GEMM1: a = gelu(x @ w1^T)   [M=T, N=F, K=H] -> bf16
    gemm_bt8<true, unsigned short>
        <<<dim3(E * (T / 256) * (F / 256)), 512, 0, stream>>>(xb, w1b, ab, T, F, H);
    // GEMM2: out = a @ w2t^T      [M=T, N=H, K=F] -> fp32
    gemm_bt8<false, float>
        <<<dim3(E * (T / 256) * (H / 256)), 512, 0, stream>>>(ab, w2t, out, T, H, F);
}